// Round 5
// baseline (277.254 us; speedup 1.0000x reference)
//
#include <hip/hip_runtime.h>
#include <math.h>

// ---------------- workspace layout (float offsets) ----------------
#define WS_E0   0       // E_s[19]
#define WS_E1   19      // E_t[19]
#define WS_G0   64      // G_s[361] (i<=j)
#define WS_G1   448     // G_t[361]
#define WS_Z    1152    // row sumexp [304]
#define WS_WBF  2048    // conv_w as bf16 [768*128] -> 49152 float slots

typedef __bf16 bf16x8 __attribute__((ext_vector_type(8)));
typedef float  f32x4  __attribute__((ext_vector_type(4)));
typedef const __attribute__((address_space(1))) unsigned int guint;
typedef       __attribute__((address_space(3))) unsigned int luint;

// ---------------- init: zero accumulators + convert W to bf16 ----------------
__global__ void k_init(const float* __restrict__ conv_w, float* __restrict__ ws,
                       float* __restrict__ out) {
    const int bx = blockIdx.x, tid = threadIdx.x;
    if (bx < 96) {
        __bf16* Wb = (__bf16*)(ws + WS_WBF);
        #pragma unroll
        for (int j = 0; j < 4; j++) {
            int idx = bx * 1024 + j * 256 + tid;
            Wb[idx] = (__bf16)conv_w[idx];
        }
    } else {
        for (int k = tid; k < 2048; k += 256) ws[k] = 0.f;
        if (tid < 2) out[tid] = 0.f;
    }
}

// ---------------- bilinear sample of t_logit row (65x65 -> 129x129) ----------------
__device__ __forceinline__ float t_resized(const float* __restrict__ Trow, int k) {
    int y = k / 129, x = k - y * 129;
    int y0 = y >> 1, x0 = x >> 1;
    int y1 = y0 + (y & 1), x1 = x0 + (x & 1);
    float fy = 0.5f * (float)(y & 1), fx = 0.5f * (float)(x & 1);
    float v00 = Trow[y0 * 65 + x0], v01 = Trow[y0 * 65 + x1];
    float v10 = Trow[y1 * 65 + x0], v11 = Trow[y1 * 65 + x1];
    float r0 = v00 + fx * (v01 - v00);
    float r1 = v10 + fx * (v11 - v10);
    return r0 + fy * (r1 - r0);
}

// ---------------- main: rowstats (0..303) + pi (304..831) + corner px (832..839) ----
// pi block = (b, strip of 64 px), ALL 768 channels as 12 chunks of 64.
// Resize computed once per strip (was 4x). Per-pixel contribution finalized
// in-block (no WS_PART round trip, no finalize dispatch).
// t buffers: B0@17408, B1@33792, B2 = xs region (dead after bfrag extraction),
// cycled c%3. A-frags afr[c%3] triple-buffered, loaded 2 chunks ahead.
// Loop fully unrolled -> every buffer index compile-time (no scratch, rule #20).
// vmcnt schedule (counts our issue order: T0,T1,A0,A1,T2 | it c: A(c+2),T(c+3)):
//   c==0:9  c in 1..9:13  c==10:9  c==11:0   -> 13 VMEM in flight under compute.
__launch_bounds__(256, 3)
__global__ void k_main(const float* __restrict__ s_out, const float* __restrict__ t_out,
                       const float* __restrict__ conv_w, const float* __restrict__ bias,
                       const float* __restrict__ s_logit, const float* __restrict__ t_logit,
                       float* __restrict__ ws, float* __restrict__ out) {
    __shared__ __align__(16) char lds[50176];
    const int tid = threadIdx.x;
    const int bx  = blockIdx.x;

    if (bx >= 304 && bx < 832) {
        // ================= pi role =================
        const int idx   = bx - 304;
        const int b     = idx / 66;
        const int strip = idx - b * 66;
        const int px0   = strip * 64;

        const int l = tid & 63, g = tid >> 6, q = l >> 4, n = l & 15;
        const int og = g * 16;                    // wave's 16 rows within each 64-chunk

        // ---- t source addressing (px rotated by 16 per 4-row group) ----
        const float* base_t = t_out + (size_t)(b * 768 + og) * 4225;
        int off[4];
        #pragma unroll
        for (int j = 0; j < 4; j++) {
            int col = ((n * 4) + j * 16) & 63;
            off[j] = (j * 4 + q) * 4225 + px0 + col;
        }
        int colr[4];
        #pragma unroll
        for (int pt = 0; pt < 4; pt++)
            colr[pt] = (((pt * 16 + (n & 12) - q * 16) & 63)) + (n & 3);

        auto issue_t = [&](int cc) {              // cc compile-time under full unroll
            int k = cc % 3;
            char* lb = (k == 2 ? lds : lds + 17408 + k * 16384) + g * 4096;
            const float* gb = base_t + (size_t)cc * 64 * 4225;
            #pragma unroll
            for (int j = 0; j < 4; j++)
                __builtin_amdgcn_global_load_lds((guint*)(gb + off[j]),
                                                 (luint*)(lb + j * 1024), 16, 0, 0);
        };

        // issue chunks 0,1 NOW: resize below hides their HBM latency
        issue_t(0);
        issue_t(1);

        __bf16* xs = (__bf16*)lds;               // 64 px x 136 c bf16

        // ---- bilinear resize 33x33 -> 65x65, 64-px strip, into xs[px][c] ----
        {
            const float* Sb = s_out + b * 128 * 1089;
            #pragma unroll
            for (int ii = 0; ii < 32; ii++) {
                int id2 = tid + ii * 256;
                int c = id2 >> 6, px = id2 & 63;
                int hw = px0 + px;
                int h = hw / 65, w = hw - h * 65;
                int y0 = h >> 1, x0 = w >> 1;
                int y1 = y0 + (h & 1), x1 = x0 + (w & 1);
                float wy = 0.5f * (float)(h & 1), wx = 0.5f * (float)(w & 1);
                const float* Sc = Sb + c * 1089;
                float v00 = Sc[y0 * 33 + x0], v01 = Sc[y0 * 33 + x1];
                float v10 = Sc[y1 * 33 + x0], v11 = Sc[y1 * 33 + x1];
                float r0 = v00 + wx * (v01 - v00);
                float r1 = v10 + wx * (v11 - v10);
                xs[px * 136 + c] = (__bf16)(r0 + wy * (r1 - r0));
            }
        }
        // barrier WITHOUT vmcnt drain (keep t0/t1 in flight)
        asm volatile("s_waitcnt lgkmcnt(0)" ::: "memory");
        __builtin_amdgcn_s_barrier();
        __builtin_amdgcn_sched_barrier(0);

        // ---- B fragments: full K=128, 4 px-groups, loaded once for all 12 chunks --
        bf16x8 bfrag[4][4];
        #pragma unroll
        for (int pt = 0; pt < 4; pt++)
            #pragma unroll
            for (int kf = 0; kf < 4; kf++)
                bfrag[pt][kf] = *(const bf16x8*)&xs[(pt * 16 + n) * 136 + kf * 32 + q * 8];

        // ---- A fragments + bias (W is L2-hot bf16), triple-buffered ----
        const __bf16* Wbf = (const __bf16*)(ws + WS_WBF);
        bf16x8 afr[3][4];
        f32x4  bq[3];
        auto load_a = [&](int cc) {               // cc compile-time under full unroll
            int s = cc % 3;
            int row0 = cc * 64 + og;
            const __bf16* Wr = Wbf + (size_t)(row0 + n) * 128 + q * 8;
            #pragma unroll
            for (int kf = 0; kf < 4; kf++) afr[s][kf] = *(const bf16x8*)(Wr + kf * 32);
            bq[s] = *(const f32x4*)&bias[row0 + q * 4];
        };
        load_a(0);
        load_a(1);

        // all waves done reading xs -> safe to overwrite with t chunk 2
        asm volatile("s_waitcnt lgkmcnt(0)" ::: "memory");
        __builtin_amdgcn_s_barrier();
        __builtin_amdgcn_sched_barrier(0);
        issue_t(2);

        float Zt[4], St[4], Dd[4], Zs[4];
        #pragma unroll
        for (int pt = 0; pt < 4; pt++) { Zt[pt] = 0.f; St[pt] = 0.f; Dd[pt] = 0.f; Zs[pt] = 0.f; }

        #pragma unroll
        for (int c = 0; c < 12; c++) {
            if (c == 0 || c == 10) asm volatile("s_waitcnt vmcnt(9)"  ::: "memory");
            else if (c == 11)      asm volatile("s_waitcnt vmcnt(0)"  ::: "memory");
            else                   asm volatile("s_waitcnt vmcnt(13)" ::: "memory");

            const int k = c % 3;
            const float* tw = (const float*)((k == 2 ? lds : lds + 17408 + k * 16384) + g * 4096);
            #pragma unroll
            for (int pt = 0; pt < 4; pt++) {
                f32x4 a0 = {0.f, 0.f, 0.f, 0.f};
                #pragma unroll
                for (int kf = 0; kf < 4; kf++)
                    a0 = __builtin_amdgcn_mfma_f32_16x16x32_bf16(afr[k][kf], bfrag[pt][kf], a0, 0, 0, 0);
                #pragma unroll
                for (int r = 0; r < 4; r++) {
                    float tv  = tw[(q * 4 + r) * 64 + colr[pt]];
                    float s1v = a0[r] + bq[k][r];
                    float e   = __expf(tv);
                    Zt[pt] += e;
                    St[pt]  = fmaf(e, tv,  St[pt]);
                    Dd[pt]  = fmaf(e, s1v, Dd[pt]);
                    Zs[pt] += __expf(s1v);
                }
            }
            if (c <= 9) load_a(c + 2);            // afr slot (c+2)%3 != k in use
            if (c <= 8) issue_t(c + 3);           // t buf c%3, compute c done
        }

        // ---- merge 16 partitions (4 waves x 4 quads) per pixel, once ----
        __syncthreads();                          // vmcnt already 0
        float* scr = (float*)lds;                 // xs/B2 region, dead now
        {
            int p = g * 4 + q;
            #pragma unroll
            for (int pt = 0; pt < 4; pt++) {
                f32x4 v = {Zt[pt], St[pt], Dd[pt], Zs[pt]};
                *(f32x4*)&scr[(pt * 16 + n) * 68 + p * 4] = v;
            }
        }
        __syncthreads();
        if (tid < 64) {
            float Z = 0.f, S = 0.f, D = 0.f, Z2 = 0.f;
            #pragma unroll
            for (int p = 0; p < 16; p++) {
                f32x4 v = *(const f32x4*)&scr[tid * 68 + p * 4];
                Z += v[0]; S += v[1]; D += v[2]; Z2 += v[3];
            }
            float contrib = (S - D) / Z - logf(Z) + logf(Z2);
            #pragma unroll
            for (int o = 32; o > 0; o >>= 1) contrib += __shfl_down(contrib, o);
            if (tid == 0) atomicAdd(out, contrib * (1.0f / 25958400.0f));
        }
    } else if (bx < 304) {
        // ================= rowstats role =================
        float* red = (float*)lds;
        int row  = bx;
        int side = (row >= 152) ? 1 : 0;
        int r    = side ? row - 152 : row;
        const float* src = side ? (t_logit + r * 4225) : (s_logit + r * 16641);

        float z = 0.f, s = 0.f;
        #pragma unroll 4
        for (int k = tid; k < 16641; k += 256) {
            float v = side ? t_resized(src, k) : src[k];
            float e = __expf(v);
            z += e;
            s = fmaf(e, v, s);
        }
        for (int off = 32; off > 0; off >>= 1) { z += __shfl_down(z, off); s += __shfl_down(s, off); }
        if ((tid & 63) == 0) { red[tid >> 6] = z; red[4 + (tid >> 6)] = s; }
        __syncthreads();
        if (tid == 0) {
            float Z = red[0] + red[1] + red[2] + red[3];
            float S = red[4] + red[5] + red[6] + red[7];
            ws[WS_Z + row] = Z;
            atomicAdd(&ws[(side ? WS_E1 : WS_E0) + (r % 19)], S / Z - logf(Z));
        }
    } else {
        // ================= corner pixel (px 4224) role, one block per b ==========
        float* xc  = (float*)lds;          // 128
        float* red = (float*)lds + 128;    // 16
        const int b = bx - 832;
        if (tid < 128) xc[tid] = s_out[((size_t)b * 128 + tid) * 1089 + 1088];
        __syncthreads();
        float z = 0.f, s = 0.f, d = 0.f, z2 = 0.f;
        #pragma unroll
        for (int rep = 0; rep < 3; rep++) {
            int o = tid + rep * 256;
            const float* Wr = conv_w + (size_t)o * 128;
            float s1 = bias[o];
            for (int cc = 0; cc < 128; cc++) s1 = fmaf(Wr[cc], xc[cc], s1);
            float tv = t_out[((size_t)(b * 768 + o)) * 4225 + 4224];
            float e  = __expf(tv);
            z += e; s = fmaf(e, tv, s); d = fmaf(e, s1, d); z2 += __expf(s1);
        }
        for (int off = 32; off > 0; off >>= 1) {
            z += __shfl_down(z, off); s += __shfl_down(s, off);
            d += __shfl_down(d, off); z2 += __shfl_down(z2, off);
        }
        if ((tid & 63) == 0) {
            int wv = tid >> 6;
            red[wv] = z; red[4 + wv] = s; red[8 + wv] = d; red[12 + wv] = z2;
        }
        __syncthreads();
        if (tid == 0) {
            float Z = red[0] + red[1] + red[2] + red[3];
            float S = red[4] + red[5] + red[6] + red[7];
            float D = red[8] + red[9] + red[10] + red[11];
            float Z2 = red[12] + red[13] + red[14] + red[15];
            float contrib = (S - D) / Z - logf(Z) + logf(Z2);
            atomicAdd(out, contrib * (1.0f / 25958400.0f));
        }
    }
}

// ---------------- mid: Gram (528 blocks, round-2 structure: max parallelism) --------
#define KT 512
#define KP 516
__global__ void k_mid(const float* __restrict__ s_logit, const float* __restrict__ t_logit,
                      float* __restrict__ ws, float* __restrict__ out) {
    __shared__ __align__(16) char lds[39296];
    const int tid = threadIdx.x;
    const int bx  = blockIdx.x;

    float* pbuf  = (float*)lds;
    float* rowiz = (float*)(lds + 39216);
    int side = (bx >= 264) ? 1 : 0;
    int rm   = side ? bx - 264 : bx;
    int b = rm / 33, kt = rm - b * 33;
    int k0 = kt * KT;

    if (tid < 19) rowiz[tid] = 1.0f / ws[WS_Z + side * 152 + b * 19 + tid];
    __syncthreads();

    for (int i = 0; i < 19; i++) {
        const float* src = side ? (t_logit + (size_t)(b * 19 + i) * 4225)
                                : (s_logit + (size_t)(b * 19 + i) * 16641);
        float iz = rowiz[i];
        #pragma unroll
        for (int kl = tid; kl < KT; kl += 256) {
            int k = k0 + kl;
            float p = 0.f;
            if (k < 16641) {
                float v = side ? t_resized(src, k) : src[k];
                p = __expf(v) * iz;
            }
            pbuf[i * KP + kl] = p;
        }
    }
    __syncthreads();

    if (tid < 190) {
        int t = tid, i = 0;
        while (t >= 19 - i) { t -= 19 - i; i++; }
        int j = i + t;
        const float* pi_ = &pbuf[i * KP];
        const float* pj_ = &pbuf[j * KP];
        float g0 = 0.f, g1 = 0.f, g2 = 0.f, g3 = 0.f;
        #pragma unroll 2
        for (int kl = 0; kl < KT; kl += 16) {
            float4 a0 = *(const float4*)&pi_[kl];      float4 c0 = *(const float4*)&pj_[kl];
            float4 a1 = *(const float4*)&pi_[kl + 4];  float4 c1 = *(const float4*)&pj_[kl + 4];
            float4 a2 = *(const float4*)&pi_[kl + 8];  float4 c2 = *(const float4*)&pj_[kl + 8];
            float4 a3 = *(const float4*)&pi_[kl + 12]; float4 c3 = *(const float4*)&pj_[kl + 12];
            g0 = fmaf(a0.x, c0.x, g0); g0 = fmaf(a0.y, c0.y, g0);
            g0 = fmaf(a0.z, c0.z, g0); g0 = fmaf(a0.w, c0.w, g0);
            g1 = fmaf(a1.x, c1.x, g1); g1 = fmaf(a1.y, c1.y, g1);
            g1 = fmaf(a1.z, c1.z, g1); g1 = fmaf(a1.w, c1.w, g1);
            g2 = fmaf(a2.x, c2.x, g2); g2 = fmaf(a2.y, c2.y, g2);
            g2 = fmaf(a2.z, c2.z, g2); g2 = fmaf(a2.w, c2.w, g2);
            g3 = fmaf(a3.x, c3.x, g3); g3 = fmaf(a3.y, c3.y, g3);
            g3 = fmaf(a3.z, c3.z, g3); g3 = fmaf(a3.w, c3.w, g3);
        }
        atomicAdd(&ws[(side ? WS_G1 : WS_G0) + i * 19 + j], (g0 + g1) + (g2 + g3));
    }
}

// ---------------- finalize lo_loss (1 block, 384 threads) ----------------
__global__ void k_final(const float* __restrict__ ws, float* __restrict__ out) {
    __shared__ float Ms[361], Mt[361], ns[19], nt[19];
    __shared__ float red[8];
    int tid = threadIdx.x;
    if (tid < 361) {
        int i = tid / 19, j = tid - i * 19;
        int lo = min(i, j), hi = max(i, j);
        Ms[tid] = (ws[WS_E0 + hi] - ws[WS_G0 + lo * 19 + hi]) * 0.125f;
        Mt[tid] = (ws[WS_E1 + hi] - ws[WS_G1 + lo * 19 + hi]) * 0.125f;
    }
    __syncthreads();
    if (tid < 19) {
        float as = 0.f, at = 0.f;
        for (int j = 0; j < 19; j++) {
            as = fmaf(Ms[tid * 19 + j], Ms[tid * 19 + j], as);
            at = fmaf(Mt[tid * 19 + j], Mt[tid * 19 + j], at);
        }
        ns[tid] = fmaxf(sqrtf(as), 1e-12f);
        nt[tid] = fmaxf(sqrtf(at), 1e-12f);
    }
    __syncthreads();
    float d = 0.f;
    if (tid < 361) {
        int i = tid / 19;
        float v = Ms[tid] / ns[i] - Mt[tid] / nt[i];
        d = v * v;
    }
    for (int off = 32; off > 0; off >>= 1) d += __shfl_down(d, off);
    if ((tid & 63) == 0) red[tid >> 6] = d;
    __syncthreads();
    if (tid == 0) out[1] = red[0] + red[1] + red[2] + red[3] + red[4] + red[5];
}

extern "C" void kernel_launch(void* const* d_in, const int* in_sizes, int n_in,
                              void* d_out, int out_size, void* d_ws, size_t ws_size,
                              hipStream_t stream) {
    const float* s_out   = (const float*)d_in[0];
    const float* t_out   = (const float*)d_in[1];
    const float* t_logit = (const float*)d_in[2];
    const float* s_logit = (const float*)d_in[3];
    const float* conv_w  = (const float*)d_in[4];
    const float* conv_b  = (const float*)d_in[5];
    float* out = (float*)d_out;
    float* ws  = (float*)d_ws;

    k_init<<<dim3(97), dim3(256), 0, stream>>>(conv_w, ws, out);
    k_main<<<dim3(840), dim3(256), 0, stream>>>(s_out, t_out, conv_w, conv_b,
                                                s_logit, t_logit, ws, out);
    k_mid<<<dim3(528), dim3(256), 0, stream>>>(s_logit, t_logit, ws, out);
    k_final<<<dim3(1), dim3(384), 0, stream>>>(ws, out);
}

// Round 6
// 262.121 us; speedup vs baseline: 1.0577x; 1.0577x over previous
//
#include <hip/hip_runtime.h>
#include <math.h>

// ---------------- workspace layout (float offsets) ----------------
#define WS_E0   0       // E_s[19]
#define WS_E1   19      // E_t[19]
#define WS_G0   64      // G_s[361] (i<=j)
#define WS_G1   448     // G_t[361]
#define WS_Z    1152    // row sumexp [304]
#define WS_WBF  2048    // conv_w as bf16 [768*128] -> 49152 float slots

typedef __bf16 bf16x8 __attribute__((ext_vector_type(8)));
typedef float  f32x4  __attribute__((ext_vector_type(4)));
typedef const __attribute__((address_space(1))) unsigned int guint;
typedef       __attribute__((address_space(3))) unsigned int luint;

// ---------------- init: zero accumulators + convert W to bf16 ----------------
__global__ void k_init(const float* __restrict__ conv_w, float* __restrict__ ws,
                       float* __restrict__ out) {
    const int bx = blockIdx.x, tid = threadIdx.x;
    if (bx < 96) {
        __bf16* Wb = (__bf16*)(ws + WS_WBF);
        #pragma unroll
        for (int j = 0; j < 4; j++) {
            int idx = bx * 1024 + j * 256 + tid;
            Wb[idx] = (__bf16)conv_w[idx];
        }
    } else {
        for (int k = tid; k < 2048; k += 256) ws[k] = 0.f;
        if (tid < 2) out[tid] = 0.f;
    }
}

// ---------------- bilinear sample of t_logit row (65x65 -> 129x129) ----------------
__device__ __forceinline__ float t_resized(const float* __restrict__ Trow, int k) {
    int y = k / 129, x = k - y * 129;
    int y0 = y >> 1, x0 = x >> 1;
    int y1 = y0 + (y & 1), x1 = x0 + (x & 1);
    float fy = 0.5f * (float)(y & 1), fx = 0.5f * (float)(x & 1);
    float v00 = Trow[y0 * 65 + x0], v01 = Trow[y0 * 65 + x1];
    float v10 = Trow[y1 * 65 + x0], v11 = Trow[y1 * 65 + x1];
    float r0 = v00 + fx * (v01 - v00);
    float r1 = v10 + fx * (v11 - v10);
    return r0 + fy * (r1 - r0);
}

// ---------------- main: pi (0..527) + rowstats (528..831) + corner (832..839) -------
// pi block = (b, strip of 64 px), ALL 768 channels as 12 macro-unrolled chunks of 64.
// All indices literal constants -> nothing can spill to scratch (rule #20).
// t buffers B0@17408 B1@33792 B2@0 (xs dead after bfrag), cycled c%3, per-wave 4KB.
// afr double-buffered: A_{c+2} issued after compute c frees slot c&1.
// VMEM program order pinned by sched_barrier(0); exact counted vmcnt:
//   prologue T0 T1 A0 A1 T2 | it c: wait, compute, A_{c+2}(c<=9), T_{c+3}(c<=8)
//   waits: c0=18 c1=23 c2..9=18 c10=14 c11=5   (A=5 ops, T=4 ops)
__launch_bounds__(256, 3)
__global__ void k_main(const float* __restrict__ s_out, const float* __restrict__ t_out,
                       const float* __restrict__ conv_w, const float* __restrict__ bias,
                       const float* __restrict__ s_logit, const float* __restrict__ t_logit,
                       float* __restrict__ ws, float* __restrict__ out) {
    __shared__ __align__(16) char lds[50176];
    const int tid = threadIdx.x;
    const int bx  = blockIdx.x;

    if (bx < 528) {
        // ================= pi role =================
        const int b     = bx / 66;
        const int strip = bx - b * 66;
        const int px0   = strip * 64;

        const int l = tid & 63, g = tid >> 6, q = l >> 4, n = l & 15;
        const int og = g * 16;                    // wave's 16 rows within each 64-chunk

        // ---- t source addressing (px rotated by 16 per 4-row group) ----
        const float* base_t = t_out + (size_t)(b * 768 + og) * 4225;
        int off[4];
        #pragma unroll
        for (int j = 0; j < 4; j++) {
            int col = ((n * 4) + j * 16) & 63;
            off[j] = (j * 4 + q) * 4225 + px0 + col;
        }
        int colr[4];
        #pragma unroll
        for (int pt = 0; pt < 4; pt++)
            colr[pt] = (((pt * 16 + (n & 12) - q * 16) & 63)) + (n & 3);

        auto issue_t = [&](int cc) {              // cc is always a literal constant
            int k = cc % 3;
            char* lb = (k == 2 ? lds : lds + 17408 + k * 16384) + g * 4096;
            const float* gb = base_t + (size_t)cc * 64 * 4225;
            #pragma unroll
            for (int j = 0; j < 4; j++)
                __builtin_amdgcn_global_load_lds((guint*)(gb + off[j]),
                                                 (luint*)(lb + j * 1024), 16, 0, 0);
        };

        issue_t(0);
        issue_t(1);           // resize below hides both chunks' HBM latency

        __bf16* xs = (__bf16*)lds;               // 64 px x 136 c bf16

        // ---- bilinear resize 33x33 -> 65x65, 64-px strip, once per strip ----
        {
            const float* Sb = s_out + b * 128 * 1089;
            #pragma unroll
            for (int ii = 0; ii < 32; ii++) {
                int id2 = tid + ii * 256;
                int c = id2 >> 6, px = id2 & 63;
                int hw = px0 + px;
                int h = hw / 65, w = hw - h * 65;
                int y0 = h >> 1, x0 = w >> 1;
                int y1 = y0 + (h & 1), x1 = x0 + (w & 1);
                float wy = 0.5f * (float)(h & 1), wx = 0.5f * (float)(w & 1);
                const float* Sc = Sb + c * 1089;
                float v00 = Sc[y0 * 33 + x0], v01 = Sc[y0 * 33 + x1];
                float v10 = Sc[y1 * 33 + x0], v11 = Sc[y1 * 33 + x1];
                float r0 = v00 + wx * (v01 - v00);
                float r1 = v10 + wx * (v11 - v10);
                xs[px * 136 + c] = (__bf16)(r0 + wy * (r1 - r0));
            }
        }
        // barrier WITHOUT vmcnt drain (keep t0/t1 in flight)
        asm volatile("s_waitcnt lgkmcnt(0)" ::: "memory");
        __builtin_amdgcn_s_barrier();
        __builtin_amdgcn_sched_barrier(0);

        // ---- B fragments: full K=128, 4 px-groups, loaded once for all 12 chunks --
        bf16x8 bfrag[4][4];
        #pragma unroll
        for (int pt = 0; pt < 4; pt++)
            #pragma unroll
            for (int kf = 0; kf < 4; kf++)
                bfrag[pt][kf] = *(const bf16x8*)&xs[(pt * 16 + n) * 136 + kf * 32 + q * 8];

        // ---- A fragments + bias (L2-hot bf16), double-buffered, static slots ----
        const __bf16* Wbf = (const __bf16*)(ws + WS_WBF);
        bf16x8 afr[2][4];
        f32x4  bq[2];
        auto load_a = [&](int cc) {               // cc literal -> slot cc&1 static
            int s = cc & 1;
            int row0 = cc * 64 + og;
            const __bf16* Wr = Wbf + (size_t)(row0 + n) * 128 + q * 8;
            #pragma unroll
            for (int kf = 0; kf < 4; kf++) afr[s][kf] = *(const bf16x8*)(Wr + kf * 32);
            bq[s] = *(const f32x4*)&bias[row0 + q * 4];
        };
        load_a(0);
        load_a(1);

        // all waves done reading xs -> safe to overwrite with t chunk 2
        asm volatile("s_waitcnt lgkmcnt(0)" ::: "memory");
        __builtin_amdgcn_s_barrier();
        __builtin_amdgcn_sched_barrier(0);
        issue_t(2);

        float Zt[4], St[4], Dd[4], Zs[4];
        #pragma unroll
        for (int pt = 0; pt < 4; pt++) { Zt[pt] = 0.f; St[pt] = 0.f; Dd[pt] = 0.f; Zs[pt] = 0.f; }

#define PI_IT(c, NW)                                                                     \
        asm volatile("s_waitcnt vmcnt(" #NW ")" ::: "memory");                           \
        __builtin_amdgcn_sched_barrier(0);                                               \
        {                                                                                \
            const float* tw = (const float*)((((c) % 3) == 2 ? lds                       \
                                : lds + 17408 + ((c) % 3) * 16384) + g * 4096);          \
            _Pragma("unroll")                                                            \
            for (int pt = 0; pt < 4; pt++) {                                             \
                f32x4 a0 = {0.f, 0.f, 0.f, 0.f};                                         \
                _Pragma("unroll")                                                        \
                for (int kf = 0; kf < 4; kf++)                                           \
                    a0 = __builtin_amdgcn_mfma_f32_16x16x32_bf16(afr[(c) & 1][kf],       \
                                               bfrag[pt][kf], a0, 0, 0, 0);              \
                _Pragma("unroll")                                                        \
                for (int r = 0; r < 4; r++) {                                            \
                    float tv  = tw[(q * 4 + r) * 64 + colr[pt]];                         \
                    float s1v = a0[r] + bq[(c) & 1][r];                                  \
                    float e   = __expf(tv);                                              \
                    Zt[pt] += e;                                                         \
                    St[pt]  = fmaf(e, tv,  St[pt]);                                      \
                    Dd[pt]  = fmaf(e, s1v, Dd[pt]);                                      \
                    Zs[pt] += __expf(s1v);                                               \
                }                                                                        \
            }                                                                            \
        }                                                                                \
        __builtin_amdgcn_sched_barrier(0);                                               \
        if ((c) <= 9) load_a((c) + 2);                                                   \
        __builtin_amdgcn_sched_barrier(0);                                               \
        if ((c) <= 8) issue_t((c) + 3);                                                  \
        __builtin_amdgcn_sched_barrier(0);

        PI_IT(0, 18)
        PI_IT(1, 23)
        PI_IT(2, 18)
        PI_IT(3, 18)
        PI_IT(4, 18)
        PI_IT(5, 18)
        PI_IT(6, 18)
        PI_IT(7, 18)
        PI_IT(8, 18)
        PI_IT(9, 18)
        PI_IT(10, 14)
        PI_IT(11, 5)
#undef PI_IT

        // ---- merge 16 partitions (4 waves x 4 quads) per pixel, once ----
        __syncthreads();
        float* scr = (float*)lds;                 // xs/B2 region, dead now
        {
            int p = g * 4 + q;
            #pragma unroll
            for (int pt = 0; pt < 4; pt++) {
                f32x4 v = {Zt[pt], St[pt], Dd[pt], Zs[pt]};
                *(f32x4*)&scr[(pt * 16 + n) * 68 + p * 4] = v;
            }
        }
        __syncthreads();
        if (tid < 64) {
            float Z = 0.f, S = 0.f, D = 0.f, Z2 = 0.f;
            #pragma unroll
            for (int p = 0; p < 16; p++) {
                f32x4 v = *(const f32x4*)&scr[tid * 68 + p * 4];
                Z += v[0]; S += v[1]; D += v[2]; Z2 += v[3];
            }
            float contrib = (S - D) / Z - logf(Z) + logf(Z2);
            #pragma unroll
            for (int o = 32; o > 0; o >>= 1) contrib += __shfl_down(contrib, o);
            if (tid == 0) atomicAdd(out, contrib * (1.0f / 25958400.0f));
        }
    } else if (bx < 832) {
        // ================= rowstats role =================
        float* red = (float*)lds;
        int row  = bx - 528;
        int side = (row >= 152) ? 1 : 0;
        int r    = side ? row - 152 : row;
        const float* src = side ? (t_logit + r * 4225) : (s_logit + r * 16641);

        float z = 0.f, s = 0.f;
        #pragma unroll 4
        for (int k = tid; k < 16641; k += 256) {
            float v = side ? t_resized(src, k) : src[k];
            float e = __expf(v);
            z += e;
            s = fmaf(e, v, s);
        }
        for (int off = 32; off > 0; off >>= 1) { z += __shfl_down(z, off); s += __shfl_down(s, off); }
        if ((tid & 63) == 0) { red[tid >> 6] = z; red[4 + (tid >> 6)] = s; }
        __syncthreads();
        if (tid == 0) {
            float Z = red[0] + red[1] + red[2] + red[3];
            float S = red[4] + red[5] + red[6] + red[7];
            ws[WS_Z + row] = Z;
            atomicAdd(&ws[(side ? WS_E1 : WS_E0) + (r % 19)], S / Z - logf(Z));
        }
    } else {
        // ================= corner pixel (px 4224) role, one block per b ==========
        float* xc  = (float*)lds;          // 128
        float* red = (float*)lds + 128;    // 16
        const int b = bx - 832;
        if (tid < 128) xc[tid] = s_out[((size_t)b * 128 + tid) * 1089 + 1088];
        __syncthreads();
        float z = 0.f, s = 0.f, d = 0.f, z2 = 0.f;
        #pragma unroll
        for (int rep = 0; rep < 3; rep++) {
            int o = tid + rep * 256;
            const float* Wr = conv_w + (size_t)o * 128;
            float s1 = bias[o];
            for (int cc = 0; cc < 128; cc++) s1 = fmaf(Wr[cc], xc[cc], s1);
            float tv = t_out[((size_t)(b * 768 + o)) * 4225 + 4224];
            float e  = __expf(tv);
            z += e; s = fmaf(e, tv, s); d = fmaf(e, s1, d); z2 += __expf(s1);
        }
        for (int off = 32; off > 0; off >>= 1) {
            z += __shfl_down(z, off); s += __shfl_down(s, off);
            d += __shfl_down(d, off); z2 += __shfl_down(z2, off);
        }
        if ((tid & 63) == 0) {
            int wv = tid >> 6;
            red[wv] = z; red[4 + wv] = s; red[8 + wv] = d; red[12 + wv] = z2;
        }
        __syncthreads();
        if (tid == 0) {
            float Z = red[0] + red[1] + red[2] + red[3];
            float S = red[4] + red[5] + red[6] + red[7];
            float D = red[8] + red[9] + red[10] + red[11];
            float Z2 = red[12] + red[13] + red[14] + red[15];
            float contrib = (S - D) / Z - logf(Z) + logf(Z2);
            atomicAdd(out, contrib * (1.0f / 25958400.0f));
        }
    }
}

// ---------------- mid: Gram (528 blocks, max parallelism) ----------------
#define KT 512
#define KP 516
__global__ void k_mid(const float* __restrict__ s_logit, const float* __restrict__ t_logit,
                      float* __restrict__ ws, float* __restrict__ out) {
    __shared__ __align__(16) char lds[39296];
    const int tid = threadIdx.x;
    const int bx  = blockIdx.x;

    float* pbuf  = (float*)lds;
    float* rowiz = (float*)(lds + 39216);
    int side = (bx >= 264) ? 1 : 0;
    int rm   = side ? bx - 264 : bx;
    int b = rm / 33, kt = rm - b * 33;
    int k0 = kt * KT;

    if (tid < 19) rowiz[tid] = 1.0f / ws[WS_Z + side * 152 + b * 19 + tid];
    __syncthreads();

    for (int i = 0; i < 19; i++) {
        const float* src = side ? (t_logit + (size_t)(b * 19 + i) * 4225)
                                : (s_logit + (size_t)(b * 19 + i) * 16641);
        float iz = rowiz[i];
        #pragma unroll
        for (int kl = tid; kl < KT; kl += 256) {
            int k = k0 + kl;
            float p = 0.f;
            if (k < 16641) {
                float v = side ? t_resized(src, k) : src[k];
                p = __expf(v) * iz;
            }
            pbuf[i * KP + kl] = p;
        }
    }
    __syncthreads();

    if (tid < 190) {
        int t = tid, i = 0;
        while (t >= 19 - i) { t -= 19 - i; i++; }
        int j = i + t;
        const float* pi_ = &pbuf[i * KP];
        const float* pj_ = &pbuf[j * KP];
        float g0 = 0.f, g1 = 0.f, g2 = 0.f, g3 = 0.f;
        #pragma unroll 2
        for (int kl = 0; kl < KT; kl += 16) {
            float4 a0 = *(const float4*)&pi_[kl];      float4 c0 = *(const float4*)&pj_[kl];
            float4 a1 = *(const float4*)&pi_[kl + 4];  float4 c1 = *(const float4*)&pj_[kl + 4];
            float4 a2 = *(const float4*)&pi_[kl + 8];  float4 c2 = *(const float4*)&pj_[kl + 8];
            float4 a3 = *(const float4*)&pi_[kl + 12]; float4 c3 = *(const float4*)&pj_[kl + 12];
            g0 = fmaf(a0.x, c0.x, g0); g0 = fmaf(a0.y, c0.y, g0);
            g0 = fmaf(a0.z, c0.z, g0); g0 = fmaf(a0.w, c0.w, g0);
            g1 = fmaf(a1.x, c1.x, g1); g1 = fmaf(a1.y, c1.y, g1);
            g1 = fmaf(a1.z, c1.z, g1); g1 = fmaf(a1.w, c1.w, g1);
            g2 = fmaf(a2.x, c2.x, g2); g2 = fmaf(a2.y, c2.y, g2);
            g2 = fmaf(a2.z, c2.z, g2); g2 = fmaf(a2.w, c2.w, g2);
            g3 = fmaf(a3.x, c3.x, g3); g3 = fmaf(a3.y, c3.y, g3);
            g3 = fmaf(a3.z, c3.z, g3); g3 = fmaf(a3.w, c3.w, g3);
        }
        atomicAdd(&ws[(side ? WS_G1 : WS_G0) + i * 19 + j], (g0 + g1) + (g2 + g3));
    }
}

// ---------------- finalize lo_loss (1 block, 384 threads) ----------------
__global__ void k_final(const float* __restrict__ ws, float* __restrict__ out) {
    __shared__ float Ms[361], Mt[361], ns[19], nt[19];
    __shared__ float red[8];
    int tid = threadIdx.x;
    if (tid < 361) {
        int i = tid / 19, j = tid - i * 19;
        int lo = min(i, j), hi = max(i, j);
        Ms[tid] = (ws[WS_E0 + hi] - ws[WS_G0 + lo * 19 + hi]) * 0.125f;
        Mt[tid] = (ws[WS_E1 + hi] - ws[WS_G1 + lo * 19 + hi]) * 0.125f;
    }
    __syncthreads();
    if (tid < 19) {
        float as = 0.f, at = 0.f;
        for (int j = 0; j < 19; j++) {
            as = fmaf(Ms[tid * 19 + j], Ms[tid * 19 + j], as);
            at = fmaf(Mt[tid * 19 + j], Mt[tid * 19 + j], at);
        }
        ns[tid] = fmaxf(sqrtf(as), 1e-12f);
        nt[tid] = fmaxf(sqrtf(at), 1e-12f);
    }
    __syncthreads();
    float d = 0.f;
    if (tid < 361) {
        int i = tid / 19;
        float v = Ms[tid] / ns[i] - Mt[tid] / nt[i];
        d = v * v;
    }
    for (int off = 32; off > 0; off >>= 1) d += __shfl_down(d, off);
    if ((tid & 63) == 0) red[tid >> 6] = d;
    __syncthreads();
    if (tid == 0) out[1] = red[0] + red[1] + red[2] + red[3] + red[4] + red[5];
}

extern "C" void kernel_launch(void* const* d_in, const int* in_sizes, int n_in,
                              void* d_out, int out_size, void* d_ws, size_t ws_size,
                              hipStream_t stream) {
    const float* s_out   = (const float*)d_in[0];
    const float* t_out   = (const float*)d_in[1];
    const float* t_logit = (const float*)d_in[2];
    const float* s_logit = (const float*)d_in[3];
    const float* conv_w  = (const float*)d_in[4];
    const float* conv_b  = (const float*)d_in[5];
    float* out = (float*)d_out;
    float* ws  = (float*)d_ws;

    k_init<<<dim3(97), dim3(256), 0, stream>>>(conv_w, ws, out);
    k_main<<<dim3(840), dim3(256), 0, stream>>>(s_out, t_out, conv_w, conv_b,
                                                s_logit, t_logit, ws, out);
    k_mid<<<dim3(528), dim3(256), 0, stream>>>(s_logit, t_logit, ws, out);
    k_final<<<dim3(1), dim3(384), 0, stream>>>(ws, out);
}

// Round 7
// 243.728 us; speedup vs baseline: 1.1376x; 1.0755x over previous
//
#include <hip/hip_runtime.h>
#include <math.h>

// ---------------- workspace layout (float offsets) ----------------
#define WS_E0   0       // E_s[19]
#define WS_E1   19      // E_t[19]
#define WS_G0   64      // G_s[361] (i<=j)
#define WS_G1   448     // G_t[361]
#define WS_Z    1152    // row sumexp [304]
#define WS_WBF  2048    // conv_w as bf16 [768*128] -> 49152 float slots

typedef __bf16 bf16x8 __attribute__((ext_vector_type(8)));
typedef float  f32x4  __attribute__((ext_vector_type(4)));
typedef const __attribute__((address_space(1))) unsigned int guint;
typedef       __attribute__((address_space(3))) unsigned int luint;

// ---------------- init: zero accumulators + convert W to bf16 ----------------
__global__ void k_init(const float* __restrict__ conv_w, float* __restrict__ ws,
                       float* __restrict__ out) {
    const int bx = blockIdx.x, tid = threadIdx.x;
    if (bx < 96) {
        __bf16* Wb = (__bf16*)(ws + WS_WBF);
        #pragma unroll
        for (int j = 0; j < 4; j++) {
            int idx = bx * 1024 + j * 256 + tid;
            Wb[idx] = (__bf16)conv_w[idx];
        }
    } else {
        for (int k = tid; k < 2048; k += 256) ws[k] = 0.f;
        if (tid < 2) out[tid] = 0.f;
    }
}

// ---------------- bilinear sample of t_logit row (65x65 -> 129x129) ----------------
__device__ __forceinline__ float t_resized(const float* __restrict__ Trow, int k) {
    int y = k / 129, x = k - y * 129;
    int y0 = y >> 1, x0 = x >> 1;
    int y1 = y0 + (y & 1), x1 = x0 + (x & 1);
    float fy = 0.5f * (float)(y & 1), fx = 0.5f * (float)(x & 1);
    float v00 = Trow[y0 * 65 + x0], v01 = Trow[y0 * 65 + x1];
    float v10 = Trow[y1 * 65 + x0], v11 = Trow[y1 * 65 + x1];
    float r0 = v00 + fx * (v01 - v00);
    float r1 = v10 + fx * (v11 - v10);
    return r0 + fy * (r1 - r0);
}

// ---------------- main: pi (0..527) + rowstats (528..831) + corner (832..839) -------
// pi block = (b, strip of 64 px), ALL 768 channels as 12 macro-unrolled chunks of 64.
// SPILL-PROOF BY CONSTRUCTION:
//  - waves_per_eu(3,3): allocator budget = 170 VGPR (LDS caps at 3 blk/CU anyway)
//  - NO bfrag array: xs persistent in LDS (stride 140 bf16 -> <=2-way banks),
//    B-fragments re-read per chunk as 4 short-lived ds_read_b128 temps
//  - A-fragments: two NAMED register sets (aA*/aB*), alternated at literal c
//  - t double-buffered 2x16KB, per-wave 4KB slices; vmcnt counts ONLY the
//    builtin t-loads (4/chunk): steady wait vmcnt(4), last vmcnt(0) --
//    correct under any compiler placement of the A/bias loads.
__global__ __launch_bounds__(256)
__attribute__((amdgpu_waves_per_eu(3, 3)))
void k_main(const float* __restrict__ s_out, const float* __restrict__ t_out,
            const float* __restrict__ conv_w, const float* __restrict__ bias,
            const float* __restrict__ s_logit, const float* __restrict__ t_logit,
            float* __restrict__ ws, float* __restrict__ out) {
    __shared__ __align__(16) char lds[50688];   // xs 17920 + 2 t-bufs 32768
    const int tid = threadIdx.x;
    const int bx  = blockIdx.x;

    if (bx < 528) {
        // ================= pi role =================
        const int b     = bx / 66;
        const int strip = bx - b * 66;
        const int px0   = strip * 64;

        const int l = tid & 63, g = tid >> 6, q = l >> 4, n = l & 15;
        const int og = g * 16;                    // wave's 16 rows within each 64-chunk

        // ---- t source addressing (px rotated by 16 per 4-row group) ----
        const float* base_t = t_out + (size_t)(b * 768 + og) * 4225;
        int off[4];
        #pragma unroll
        for (int j = 0; j < 4; j++) {
            int col = ((n * 4) + j * 16) & 63;
            off[j] = (j * 4 + q) * 4225 + px0 + col;
        }
        int colr[4];
        #pragma unroll
        for (int pt = 0; pt < 4; pt++)
            colr[pt] = (((pt * 16 + (n & 12) - q * 16) & 63)) + (n & 3);

        auto issue_t = [&](int cc) {              // cc always literal; buf = cc&1
            char* lb = lds + 17920 + (cc & 1) * 16384 + g * 4096;
            const float* gb = base_t + (size_t)cc * 64 * 4225;
            #pragma unroll
            for (int j = 0; j < 4; j++)
                __builtin_amdgcn_global_load_lds((guint*)(gb + off[j]),
                                                 (luint*)(lb + j * 1024), 16, 0, 0);
        };

        issue_t(0);
        issue_t(1);           // resize below hides both chunks' HBM latency

        __bf16* xs = (__bf16*)lds;               // 64 px x 140 c bf16 (padded stride)

        // ---- bilinear resize 33x33 -> 65x65, 64-px strip, once per strip ----
        {
            const float* Sb = s_out + b * 128 * 1089;
            #pragma unroll
            for (int ii = 0; ii < 32; ii++) {
                int id2 = tid + ii * 256;
                int c = id2 >> 6, px = id2 & 63;
                int hw = px0 + px;
                int h = hw / 65, w = hw - h * 65;
                int y0 = h >> 1, x0 = w >> 1;
                int y1 = y0 + (h & 1), x1 = x0 + (w & 1);
                float wy = 0.5f * (float)(h & 1), wx = 0.5f * (float)(w & 1);
                const float* Sc = Sb + c * 1089;
                float v00 = Sc[y0 * 33 + x0], v01 = Sc[y0 * 33 + x1];
                float v10 = Sc[y1 * 33 + x0], v11 = Sc[y1 * 33 + x1];
                float r0 = v00 + wx * (v01 - v00);
                float r1 = v10 + wx * (v11 - v10);
                xs[px * 140 + c] = (__bf16)(r0 + wy * (r1 - r0));
            }
        }
        // barrier WITHOUT vmcnt drain (keep t0/t1 in flight); xs stable hereafter
        asm volatile("s_waitcnt lgkmcnt(0)" ::: "memory");
        __builtin_amdgcn_s_barrier();
        __builtin_amdgcn_sched_barrier(0);

        const __bf16* Wbf = (const __bf16*)(ws + WS_WBF);
        bf16x8 aA0, aA1, aA2, aA3, aB0, aB1, aB2, aB3;
        f32x4  bqA, bqB;

#define LOAD_A(cc, A0_, A1_, A2_, A3_, BQ_) do {                                          \
        const __bf16* Wr_ = Wbf + (size_t)((cc) * 64 + og + n) * 128 + q * 8;             \
        A0_ = *(const bf16x8*)(Wr_);       A1_ = *(const bf16x8*)(Wr_ + 32);              \
        A2_ = *(const bf16x8*)(Wr_ + 64);  A3_ = *(const bf16x8*)(Wr_ + 96);              \
        BQ_ = *(const f32x4*)&bias[(cc) * 64 + og + q * 4];                               \
    } while (0)

        LOAD_A(0, aA0, aA1, aA2, aA3, bqA);

        float Zt[4], St[4], Dd[4], Zs[4];
        #pragma unroll
        for (int pt = 0; pt < 4; pt++) { Zt[pt] = 0.f; St[pt] = 0.f; Dd[pt] = 0.f; Zs[pt] = 0.f; }

#define PI_STEP(c, NW, A0_, A1_, A2_, A3_, BQ_, NA0_, NA1_, NA2_, NA3_, NBQ_)             \
        asm volatile("s_waitcnt vmcnt(" #NW ")" ::: "memory");                            \
        if ((c) < 11) LOAD_A((c) + 1, NA0_, NA1_, NA2_, NA3_, NBQ_);                      \
        {                                                                                 \
            const float* tw_ = (const float*)(lds + 17920 + ((c) & 1) * 16384 + g * 4096);\
            _Pragma("unroll")                                                             \
            for (int pt = 0; pt < 4; pt++) {                                              \
                const __bf16* bx_ = &xs[(pt * 16 + n) * 140 + q * 8];                     \
                bf16x8 b0_ = *(const bf16x8*)(bx_);                                       \
                bf16x8 b1_ = *(const bf16x8*)(bx_ + 32);                                  \
                bf16x8 b2_ = *(const bf16x8*)(bx_ + 64);                                  \
                bf16x8 b3_ = *(const bf16x8*)(bx_ + 96);                                  \
                f32x4 a0_ = {0.f, 0.f, 0.f, 0.f};                                         \
                a0_ = __builtin_amdgcn_mfma_f32_16x16x32_bf16(A0_, b0_, a0_, 0, 0, 0);    \
                a0_ = __builtin_amdgcn_mfma_f32_16x16x32_bf16(A1_, b1_, a0_, 0, 0, 0);    \
                a0_ = __builtin_amdgcn_mfma_f32_16x16x32_bf16(A2_, b2_, a0_, 0, 0, 0);    \
                a0_ = __builtin_amdgcn_mfma_f32_16x16x32_bf16(A3_, b3_, a0_, 0, 0, 0);    \
                _Pragma("unroll")                                                         \
                for (int r = 0; r < 4; r++) {                                             \
                    float tv  = tw_[(q * 4 + r) * 64 + colr[pt]];                         \
                    float s1v = a0_[r] + BQ_[r];                                          \
                    float e   = __expf(tv);                                               \
                    Zt[pt] += e;                                                          \
                    St[pt]  = fmaf(e, tv,  St[pt]);                                       \
                    Dd[pt]  = fmaf(e, s1v, Dd[pt]);                                       \
                    Zs[pt] += __expf(s1v);                                                \
                }                                                                         \
            }                                                                             \
        }                                                                                 \
        if ((c) <= 9) issue_t((c) + 2);

        PI_STEP(0,  4, aA0, aA1, aA2, aA3, bqA, aB0, aB1, aB2, aB3, bqB)
        PI_STEP(1,  4, aB0, aB1, aB2, aB3, bqB, aA0, aA1, aA2, aA3, bqA)
        PI_STEP(2,  4, aA0, aA1, aA2, aA3, bqA, aB0, aB1, aB2, aB3, bqB)
        PI_STEP(3,  4, aB0, aB1, aB2, aB3, bqB, aA0, aA1, aA2, aA3, bqA)
        PI_STEP(4,  4, aA0, aA1, aA2, aA3, bqA, aB0, aB1, aB2, aB3, bqB)
        PI_STEP(5,  4, aB0, aB1, aB2, aB3, bqB, aA0, aA1, aA2, aA3, bqA)
        PI_STEP(6,  4, aA0, aA1, aA2, aA3, bqA, aB0, aB1, aB2, aB3, bqB)
        PI_STEP(7,  4, aB0, aB1, aB2, aB3, bqB, aA0, aA1, aA2, aA3, bqA)
        PI_STEP(8,  4, aA0, aA1, aA2, aA3, bqA, aB0, aB1, aB2, aB3, bqB)
        PI_STEP(9,  4, aB0, aB1, aB2, aB3, bqB, aA0, aA1, aA2, aA3, bqA)
        PI_STEP(10, 4, aA0, aA1, aA2, aA3, bqA, aB0, aB1, aB2, aB3, bqB)
        PI_STEP(11, 0, aB0, aB1, aB2, aB3, bqB, aA0, aA1, aA2, aA3, bqA)
#undef PI_STEP
#undef LOAD_A

        // ---- merge 16 partitions (4 waves x 4 quads) per pixel, once ----
        __syncthreads();                          // vmcnt already 0
        float* scr = (float*)lds;                 // xs region, dead now (64*68*4=17408)
        {
            int p = g * 4 + q;
            #pragma unroll
            for (int pt = 0; pt < 4; pt++) {
                f32x4 v = {Zt[pt], St[pt], Dd[pt], Zs[pt]};
                *(f32x4*)&scr[(pt * 16 + n) * 68 + p * 4] = v;
            }
        }
        __syncthreads();
        if (tid < 64) {
            float Z = 0.f, S = 0.f, D = 0.f, Z2 = 0.f;
            #pragma unroll
            for (int p = 0; p < 16; p++) {
                f32x4 v = *(const f32x4*)&scr[tid * 68 + p * 4];
                Z += v[0]; S += v[1]; D += v[2]; Z2 += v[3];
            }
            float contrib = (S - D) / Z - logf(Z) + logf(Z2);
            #pragma unroll
            for (int o = 32; o > 0; o >>= 1) contrib += __shfl_down(contrib, o);
            if (tid == 0) atomicAdd(out, contrib * (1.0f / 25958400.0f));
        }
    } else if (bx < 832) {
        // ================= rowstats role =================
        float* red = (float*)lds;
        int row  = bx - 528;
        int side = (row >= 152) ? 1 : 0;
        int r    = side ? row - 152 : row;
        const float* src = side ? (t_logit + r * 4225) : (s_logit + r * 16641);

        float z = 0.f, s = 0.f;
        #pragma unroll 4
        for (int k = tid; k < 16641; k += 256) {
            float v = side ? t_resized(src, k) : src[k];
            float e = __expf(v);
            z += e;
            s = fmaf(e, v, s);
        }
        for (int off = 32; off > 0; off >>= 1) { z += __shfl_down(z, off); s += __shfl_down(s, off); }
        if ((tid & 63) == 0) { red[tid >> 6] = z; red[4 + (tid >> 6)] = s; }
        __syncthreads();
        if (tid == 0) {
            float Z = red[0] + red[1] + red[2] + red[3];
            float S = red[4] + red[5] + red[6] + red[7];
            ws[WS_Z + row] = Z;
            atomicAdd(&ws[(side ? WS_E1 : WS_E0) + (r % 19)], S / Z - logf(Z));
        }
    } else {
        // ================= corner pixel (px 4224) role, one block per b ==========
        float* xc  = (float*)lds;          // 128
        float* red = (float*)lds + 128;    // 16
        const int b = bx - 832;
        if (tid < 128) xc[tid] = s_out[((size_t)b * 128 + tid) * 1089 + 1088];
        __syncthreads();
        float z = 0.f, s = 0.f, d = 0.f, z2 = 0.f;
        #pragma unroll
        for (int rep = 0; rep < 3; rep++) {
            int o = tid + rep * 256;
            const float* Wr = conv_w + (size_t)o * 128;
            float s1 = bias[o];
            for (int cc = 0; cc < 128; cc++) s1 = fmaf(Wr[cc], xc[cc], s1);
            float tv = t_out[((size_t)(b * 768 + o)) * 4225 + 4224];
            float e  = __expf(tv);
            z += e; s = fmaf(e, tv, s); d = fmaf(e, s1, d); z2 += __expf(s1);
        }
        for (int off = 32; off > 0; off >>= 1) {
            z += __shfl_down(z, off); s += __shfl_down(s, off);
            d += __shfl_down(d, off); z2 += __shfl_down(z2, off);
        }
        if ((tid & 63) == 0) {
            int wv = tid >> 6;
            red[wv] = z; red[4 + wv] = s; red[8 + wv] = d; red[12 + wv] = z2;
        }
        __syncthreads();
        if (tid == 0) {
            float Z = red[0] + red[1] + red[2] + red[3];
            float S = red[4] + red[5] + red[6] + red[7];
            float D = red[8] + red[9] + red[10] + red[11];
            float Z2 = red[12] + red[13] + red[14] + red[15];
            float contrib = (S - D) / Z - logf(Z) + logf(Z2);
            atomicAdd(out, contrib * (1.0f / 25958400.0f));
        }
    }
}

// ---------------- mid: Gram (528 blocks, max parallelism) ----------------
#define KT 512
#define KP 516
__global__ void k_mid(const float* __restrict__ s_logit, const float* __restrict__ t_logit,
                      float* __restrict__ ws, float* __restrict__ out) {
    __shared__ __align__(16) char lds[39296];
    const int tid = threadIdx.x;
    const int bx  = blockIdx.x;

    float* pbuf  = (float*)lds;
    float* rowiz = (float*)(lds + 39216);
    int side = (bx >= 264) ? 1 : 0;
    int rm   = side ? bx - 264 : bx;
    int b = rm / 33, kt = rm - b * 33;
    int k0 = kt * KT;

    if (tid < 19) rowiz[tid] = 1.0f / ws[WS_Z + side * 152 + b * 19 + tid];
    __syncthreads();

    for (int i = 0; i < 19; i++) {
        const float* src = side ? (t_logit + (size_t)(b * 19 + i) * 4225)
                                : (s_logit + (size_t)(b * 19 + i) * 16641);
        float iz = rowiz[i];
        #pragma unroll
        for (int kl = tid; kl < KT; kl += 256) {
            int k = k0 + kl;
            float p = 0.f;
            if (k < 16641) {
                float v = side ? t_resized(src, k) : src[k];
                p = __expf(v) * iz;
            }
            pbuf[i * KP + kl] = p;
        }
    }
    __syncthreads();

    if (tid < 190) {
        int t = tid, i = 0;
        while (t >= 19 - i) { t -= 19 - i; i++; }
        int j = i + t;
        const float* pi_ = &pbuf[i * KP];
        const float* pj_ = &pbuf[j * KP];
        float g0 = 0.f, g1 = 0.f, g2 = 0.f, g3 = 0.f;
        #pragma unroll 2
        for (int kl = 0; kl < KT; kl += 16) {
            float4 a0 = *(const float4*)&pi_[kl];      float4 c0 = *(const float4*)&pj_[kl];
            float4 a1 = *(const float4*)&pi_[kl + 4];  float4 c1 = *(const float4*)&pj_[kl + 4];
            float4 a2 = *(const float4*)&pi_[kl + 8];  float4 c2 = *(const float4*)&pj_[kl + 8];
            float4 a3 = *(const float4*)&pi_[kl + 12]; float4 c3 = *(const float4*)&pj_[kl + 12];
            g0 = fmaf(a0.x, c0.x, g0); g0 = fmaf(a0.y, c0.y, g0);
            g0 = fmaf(a0.z, c0.z, g0); g0 = fmaf(a0.w, c0.w, g0);
            g1 = fmaf(a1.x, c1.x, g1); g1 = fmaf(a1.y, c1.y, g1);
            g1 = fmaf(a1.z, c1.z, g1); g1 = fmaf(a1.w, c1.w, g1);
            g2 = fmaf(a2.x, c2.x, g2); g2 = fmaf(a2.y, c2.y, g2);
            g2 = fmaf(a2.z, c2.z, g2); g2 = fmaf(a2.w, c2.w, g2);
            g3 = fmaf(a3.x, c3.x, g3); g3 = fmaf(a3.y, c3.y, g3);
            g3 = fmaf(a3.z, c3.z, g3); g3 = fmaf(a3.w, c3.w, g3);
        }
        atomicAdd(&ws[(side ? WS_G1 : WS_G0) + i * 19 + j], (g0 + g1) + (g2 + g3));
    }
}

// ---------------- finalize lo_loss (1 block, 384 threads) ----------------
__global__ void k_final(const float* __restrict__ ws, float* __restrict__ out) {
    __shared__ float Ms[361], Mt[361], ns[19], nt[19];
    __shared__ float red[8];
    int tid = threadIdx.x;
    if (tid < 361) {
        int i = tid / 19, j = tid - i * 19;
        int lo = min(i, j), hi = max(i, j);
        Ms[tid] = (ws[WS_E0 + hi] - ws[WS_G0 + lo * 19 + hi]) * 0.125f;
        Mt[tid] = (ws[WS_E1 + hi] - ws[WS_G1 + lo * 19 + hi]) * 0.125f;
    }
    __syncthreads();
    if (tid < 19) {
        float as = 0.f, at = 0.f;
        for (int j = 0; j < 19; j++) {
            as = fmaf(Ms[tid * 19 + j], Ms[tid * 19 + j], as);
            at = fmaf(Mt[tid * 19 + j], Mt[tid * 19 + j], at);
        }
        ns[tid] = fmaxf(sqrtf(as), 1e-12f);
        nt[tid] = fmaxf(sqrtf(at), 1e-12f);
    }
    __syncthreads();
    float d = 0.f;
    if (tid < 361) {
        int i = tid / 19;
        float v = Ms[tid] / ns[i] - Mt[tid] / nt[i];
        d = v * v;
    }
    for (int off = 32; off > 0; off >>= 1) d += __shfl_down(d, off);
    if ((tid & 63) == 0) red[tid >> 6] = d;
    __syncthreads();
    if (tid == 0) out[1] = red[0] + red[1] + red[2] + red[3] + red[4] + red[5];
}

extern "C" void kernel_launch(void* const* d_in, const int* in_sizes, int n_in,
                              void* d_out, int out_size, void* d_ws, size_t ws_size,
                              hipStream_t stream) {
    const float* s_out   = (const float*)d_in[0];
    const float* t_out   = (const float*)d_in[1];
    const float* t_logit = (const float*)d_in[2];
    const float* s_logit = (const float*)d_in[3];
    const float* conv_w  = (const float*)d_in[4];
    const float* conv_b  = (const float*)d_in[5];
    float* out = (float*)d_out;
    float* ws  = (float*)d_ws;

    k_init<<<dim3(97), dim3(256), 0, stream>>>(conv_w, ws, out);
    k_main<<<dim3(840), dim3(256), 0, stream>>>(s_out, t_out, conv_w, conv_b,
                                                s_logit, t_logit, ws, out);
    k_mid<<<dim3(528), dim3(256), 0, stream>>>(s_logit, t_logit, ws, out);
    k_final<<<dim3(1), dim3(384), 0, stream>>>(ws, out);
}